// Round 1
// baseline (9947.057 us; speedup 1.0000x reference)
//
#include <hip/hip_runtime.h>
#include <math.h>

#define M_ROWS 2048      // B*T
#define N_KEYS 65536
#define DKK 512
#define DVV 512
#define KTOP 32
#define NSPLIT 32        // N split across blocks
#define QB 128           // q-rows per block
#define NB 128           // keys per tile
#define KC 32            // k-chunk
#define NRANGE (N_KEYS / NSPLIT)   // 2048
#define NTILES (NRANGE / NB)       // 16
#define KCH (DKK / KC)             // 16
#define LDST 132                   // padded LDS row stride (floats)

// ---------------- normalize: qn rows + key inverse norms ----------------
__global__ void __launch_bounds__(256) norm_kernel(
    const float* __restrict__ q, const float* __restrict__ keys,
    float* __restrict__ qn, float* __restrict__ kinv) {
  const int gw = (blockIdx.x * 256 + threadIdx.x) >> 6;  // global wave id
  const int lane = threadIdx.x & 63;
  if (gw < M_ROWS) {
    const float* row = q + (size_t)gw * DKK;
    float4 a = ((const float4*)row)[lane];
    float4 b = ((const float4*)row)[lane + 64];
    float s = a.x*a.x + a.y*a.y + a.z*a.z + a.w*a.w
            + b.x*b.x + b.y*b.y + b.z*b.z + b.w*b.w;
#pragma unroll
    for (int off = 32; off; off >>= 1) s += __shfl_xor(s, off);
    const float inv = 1.0f / fmaxf(sqrtf(s), 1e-12f);
    float* orow = qn + (size_t)gw * DKK;
    ((float4*)orow)[lane]      = make_float4(a.x*inv, a.y*inv, a.z*inv, a.w*inv);
    ((float4*)orow)[lane + 64] = make_float4(b.x*inv, b.y*inv, b.z*inv, b.w*inv);
  } else {
    const int n = gw - M_ROWS;
    if (n < N_KEYS) {
      const float* row = keys + (size_t)n * DKK;
      float4 a = ((const float4*)row)[lane];
      float4 b = ((const float4*)row)[lane + 64];
      float s = a.x*a.x + a.y*a.y + a.z*a.z + a.w*a.w
              + b.x*b.x + b.y*b.y + b.z*b.z + b.w*b.w;
#pragma unroll
      for (int off = 32; off; off >>= 1) s += __shfl_xor(s, off);
      if (lane == 0) kinv[n] = 1.0f / fmaxf(sqrtf(s), 1e-12f);
    }
  }
}

// transposed LDS staging write: dst[kk][r], kk = k8*4..k8*4+3
__device__ __forceinline__ void lds_wr_tile(float* dst, int k8, int r, float4 v, float scale) {
  dst[(k8 * 4 + 0) * LDST + r] = v.x * scale;
  dst[(k8 * 4 + 1) * LDST + r] = v.y * scale;
  dst[(k8 * 4 + 2) * LDST + r] = v.z * scale;
  dst[(k8 * 4 + 3) * LDST + r] = v.w * scale;
}

// ---------------- fused score GEMM + running per-row top-32 ----------------
__global__ void __launch_bounds__(256, 1) score_topk_kernel(
    const float* __restrict__ qn, const float* __restrict__ keys,
    const float* __restrict__ kinv,
    float* __restrict__ pscore, int* __restrict__ pidx) {
  // u unions: [A0|B0|A1|B1] staging (4*32*132) == score tile S[128][132] (16896 floats)
  __shared__ float u[16896];
  __shared__ float topS[QB * KTOP];
  __shared__ int   topI[QB * KTOP];

  const int tid = threadIdx.x;
  const int tx = tid & 15, ty = tid >> 4;
  const int qbase = blockIdx.y * QB;
  const int nbase0 = blockIdx.x * NRANGE;

  for (int i = tid; i < QB * KTOP; i += 256) { topS[i] = -INFINITY; topI[i] = 0; }
  __syncthreads();

  for (int t = 0; t < NTILES; ++t) {
    const int n0 = nbase0 + t * NB;
    float acc[8][8];
#pragma unroll
    for (int i = 0; i < 8; ++i)
#pragma unroll
      for (int j = 0; j < 8; ++j) acc[i][j] = 0.0f;

    // stage chunk 0 into buf 0
#pragma unroll
    for (int p = 0; p < 4; ++p) {
      const int id = tid + p * 256;
      const int r = id >> 3, k8 = id & 7;
      const float4 va = *(const float4*)&qn[(size_t)(qbase + r) * DKK + k8 * 4];
      const float4 vb = *(const float4*)&keys[(size_t)(n0 + r) * DKK + k8 * 4];
      const float kv = kinv[n0 + r];
      lds_wr_tile(u, k8, r, va, 1.0f);
      lds_wr_tile(u + 4224, k8, r, vb, kv);
    }
    __syncthreads();

    for (int kc = 0; kc < KCH; ++kc) {
      float4 pa[4], pb[4]; float pk[4];
      const bool pre = (kc + 1 < KCH);
      if (pre) {
#pragma unroll
        for (int p = 0; p < 4; ++p) {
          const int id = tid + p * 256;
          const int r = id >> 3, k8 = id & 7;
          pa[p] = *(const float4*)&qn[(size_t)(qbase + r) * DKK + (kc + 1) * KC + k8 * 4];
          pb[p] = *(const float4*)&keys[(size_t)(n0 + r) * DKK + (kc + 1) * KC + k8 * 4];
          pk[p] = kinv[n0 + r];
        }
      }
      const float* As = u + (kc & 1) * 8448;
      const float* Bs = As + 4224;
#pragma unroll 4
      for (int kk = 0; kk < KC; ++kk) {
        const float4 a0 = *(const float4*)&As[kk * LDST + ty * 4];
        const float4 a1 = *(const float4*)&As[kk * LDST + ty * 4 + 64];
        const float4 b0 = *(const float4*)&Bs[kk * LDST + tx * 4];
        const float4 b1 = *(const float4*)&Bs[kk * LDST + tx * 4 + 64];
        const float av[8] = {a0.x,a0.y,a0.z,a0.w,a1.x,a1.y,a1.z,a1.w};
        const float bv[8] = {b0.x,b0.y,b0.z,b0.w,b1.x,b1.y,b1.z,b1.w};
#pragma unroll
        for (int i = 0; i < 8; ++i)
#pragma unroll
          for (int j = 0; j < 8; ++j)
            acc[i][j] = fmaf(av[i], bv[j], acc[i][j]);
      }
      if (pre) {
        float* Ad = u + ((kc + 1) & 1) * 8448;
        float* Bd = Ad + 4224;
#pragma unroll
        for (int p = 0; p < 4; ++p) {
          const int id = tid + p * 256;
          const int r = id >> 3, k8 = id & 7;
          lds_wr_tile(Ad, k8, r, pa[p], 1.0f);
          lds_wr_tile(Bd, k8, r, pb[p], pk[p]);
        }
      }
      __syncthreads();
    }

    // write 128x128 score tile into u (staging dead now)
#pragma unroll
    for (int ib = 0; ib < 2; ++ib)
#pragma unroll
      for (int i = 0; i < 4; ++i) {
        const int r = ty * 4 + i + ib * 64;
#pragma unroll
        for (int jb = 0; jb < 2; ++jb) {
          *(float4*)&u[r * LDST + tx * 4 + jb * 64] =
              make_float4(acc[ib*4+i][jb*4+0], acc[ib*4+i][jb*4+1],
                          acc[ib*4+i][jb*4+2], acc[ib*4+i][jb*4+3]);
        }
      }
    __syncthreads();

    // one owner thread per row: scan tile, maintain exact sorted top-32
    if (tid < QB) {
      const int row = tid;
      float* tS = &topS[row * KTOP];
      int*   tI = &topI[row * KTOP];
      float mS = tS[KTOP - 1]; int mI = tI[KTOP - 1];
      for (int c4 = 0; c4 < NB / 4; ++c4) {
        const float4 v = *(const float4*)&u[row * LDST + c4 * 4];
#pragma unroll
        for (int w = 0; w < 4; ++w) {
          const float s = (&v.x)[w];
          const int idx = n0 + c4 * 4 + w;
          if (s > mS || (s == mS && idx < mI)) {
            int p = 0;
            while (p < KTOP && (tS[p] > s || (tS[p] == s && tI[p] < idx))) ++p;
            for (int qq = KTOP - 1; qq > p; --qq) { tS[qq] = tS[qq-1]; tI[qq] = tI[qq-1]; }
            tS[p] = s; tI[p] = idx;
            mS = tS[KTOP - 1]; mI = tI[KTOP - 1];
          }
        }
      }
    }
    __syncthreads();
  }

  if (tid < QB) {
    const size_t base = ((size_t)(qbase + tid) * NSPLIT + blockIdx.x) * KTOP;
    for (int j = 0; j < KTOP; ++j) {
      pscore[base + j] = topS[tid * KTOP + j];
      pidx[base + j]   = topI[tid * KTOP + j];
    }
  }
}

// ---------- merge 32 sorted partial lists, softmax, gather+aggregate ----------
__global__ void __launch_bounds__(256) merge_kernel(
    const float* __restrict__ pscore, const int* __restrict__ pidx,
    const float* __restrict__ values,
    float* __restrict__ out_agg, float* __restrict__ out_attn, float* __restrict__ out_idx) {
  __shared__ float attn_s[KTOP];
  __shared__ int   sel_i[KTOP];
  const int row = blockIdx.x;
  const int tid = threadIdx.x;

  if (tid < 64) {
    const int lane = tid;
    const float* ps = pscore + (size_t)row * NSPLIT * KTOP;
    const int*   pi = pidx   + (size_t)row * NSPLIT * KTOP;
    int pos = 0;
    float s; int idx;
    if (lane < NSPLIT) { s = ps[lane * KTOP]; idx = pi[lane * KTOP]; }
    else { s = -INFINITY; idx = 0x7fffffff; }
    for (int it = 0; it < KTOP; ++it) {
      float ws = s; int wi = idx; int wl = lane;
#pragma unroll
      for (int off = 32; off; off >>= 1) {
        const float os = __shfl_xor(ws, off);
        const int   oi = __shfl_xor(wi, off);
        const int   ol = __shfl_xor(wl, off);
        if (os > ws || (os == ws && oi < wi)) { ws = os; wi = oi; wl = ol; }
      }
      if (lane == 0) { attn_s[it] = ws; sel_i[it] = wi; }  // scores for now
      if (lane == wl) {
        ++pos;
        if (pos < KTOP) { s = ps[lane * KTOP + pos]; idx = pi[lane * KTOP + pos]; }
        else { s = -INFINITY; idx = 0x7fffffff; }
      }
    }
  }
  __syncthreads();
  if (tid < KTOP) {
    const float m = attn_s[0];                  // list is descending
    const float e = expf((attn_s[tid] - m) * 10.0f);  // /0.1
    float tsum = e;
#pragma unroll
    for (int off = 16; off; off >>= 1) tsum += __shfl_xor(tsum, off);
    const float a = e / tsum;
    out_attn[(size_t)row * KTOP + tid] = a;
    out_idx [(size_t)row * KTOP + tid] = (float)sel_i[tid];
    attn_s[tid] = a;
  }
  __syncthreads();

  const int d = tid * 2;
  float2 accv = make_float2(0.0f, 0.0f);
  for (int j = 0; j < KTOP; ++j) {
    const float w = attn_s[j];
    const float2 v = *(const float2*)&values[(size_t)sel_i[j] * DVV + d];
    accv.x = fmaf(w, v.x, accv.x);
    accv.y = fmaf(w, v.y, accv.y);
  }
  *(float2*)&out_agg[(size_t)row * DVV + d] = accv;
}

extern "C" void kernel_launch(void* const* d_in, const int* in_sizes, int n_in,
                              void* d_out, int out_size, void* d_ws, size_t ws_size,
                              hipStream_t stream) {
  const float* q      = (const float*)d_in[0];
  const float* keys   = (const float*)d_in[1];
  const float* values = (const float*)d_in[2];

  float* ws    = (float*)d_ws;
  float* qn    = ws;                                   // 2048*512
  float* kinv  = qn + (size_t)M_ROWS * DKK;            // 65536
  float* pscore = kinv + N_KEYS;                       // 2048*32*32
  int*   pidx  = (int*)(pscore + (size_t)M_ROWS * NSPLIT * KTOP);

  float* out      = (float*)d_out;
  float* out_agg  = out;                               // 2048*512
  float* out_attn = out + (size_t)M_ROWS * DVV;        // 2048*32
  float* out_idx  = out_attn + (size_t)M_ROWS * KTOP;  // 2048*32

  norm_kernel<<<(M_ROWS + N_KEYS) / 4, 256, 0, stream>>>(q, keys, qn, kinv);
  dim3 g2(NSPLIT, M_ROWS / QB, 1);
  score_topk_kernel<<<g2, 256, 0, stream>>>(qn, keys, kinv, pscore, pidx);
  merge_kernel<<<M_ROWS, 256, 0, stream>>>(pscore, pidx, values, out_agg, out_attn, out_idx);
}

// Round 2
// 1569.115 us; speedup vs baseline: 6.3393x; 6.3393x over previous
//
#include <hip/hip_runtime.h>
#include <math.h>

#define M_ROWS 2048
#define N_KEYS 65536
#define DKK 512
#define DVV 512
#define KTOP 32
#define NSPLIT 32
#define NRANGE (N_KEYS / NSPLIT)   // 2048
#define BM 128
#define BN 128
#define NTILES (NRANGE / BN)       // 16
#define KSTEPS (DKK / 32)          // 16
#define CAP 8                      // candidate bucket capacity per row per round

typedef _Float16 f16x8 __attribute__((ext_vector_type(8)));
typedef _Float16 f16x4v __attribute__((ext_vector_type(4)));
typedef float f32x4 __attribute__((ext_vector_type(4)));

// ===================== FAST PATH =====================

__device__ __forceinline__ void split4(const float4 v, float inv,
                                       _Float16* ph, _Float16* pl) {
  f16x4v h, l;
  float y;
  y = v.x * inv; h[0] = (_Float16)y; l[0] = (_Float16)(y - (float)h[0]);
  y = v.y * inv; h[1] = (_Float16)y; l[1] = (_Float16)(y - (float)h[1]);
  y = v.z * inv; h[2] = (_Float16)y; l[2] = (_Float16)(y - (float)h[2]);
  y = v.w * inv; h[3] = (_Float16)y; l[3] = (_Float16)(y - (float)h[3]);
  *(f16x4v*)ph = h; *(f16x4v*)pl = l;
}

__global__ void __launch_bounds__(256) norm_split_kernel(
    const float* __restrict__ q, const float* __restrict__ keys,
    _Float16* __restrict__ Qh, _Float16* __restrict__ Ql,
    _Float16* __restrict__ Kh, _Float16* __restrict__ Kl) {
  const int gw = (blockIdx.x * 256 + threadIdx.x) >> 6;
  const int lane = threadIdx.x & 63;
  const float* row; _Float16 *oh, *ol;
  if (gw < M_ROWS) {
    row = q + (size_t)gw * DKK; oh = Qh + (size_t)gw * DKK; ol = Ql + (size_t)gw * DKK;
  } else {
    const int n = gw - M_ROWS;
    if (n >= N_KEYS) return;
    row = keys + (size_t)n * DKK; oh = Kh + (size_t)n * DKK; ol = Kl + (size_t)n * DKK;
  }
  const float4 a = ((const float4*)row)[lane];
  const float4 b = ((const float4*)row)[lane + 64];
  float s = a.x*a.x + a.y*a.y + a.z*a.z + a.w*a.w
          + b.x*b.x + b.y*b.y + b.z*b.z + b.w*b.w;
#pragma unroll
  for (int off = 32; off; off >>= 1) s += __shfl_xor(s, off);
  const float inv = 1.0f / fmaxf(sqrtf(s), 1e-12f);
  split4(a, inv, oh + lane * 4,       ol + lane * 4);
  split4(b, inv, oh + 256 + lane * 4, ol + 256 + lane * 4);
}

// owner-thread exact insertion into sorted (score desc, idx asc) 32-list
__device__ __forceinline__ void insert32(float* tS, int* tI, float s, int idx) {
  const float ms = tS[31]; const int mi_ = tI[31];
  if (s < ms || (s == ms && idx > mi_)) return;
  int p = 0;
  while (p < KTOP && (tS[p] > s || (tS[p] == s && tI[p] < idx))) ++p;
  for (int qq = KTOP - 1; qq > p; --qq) { tS[qq] = tS[qq-1]; tI[qq] = tI[qq-1]; }
  tS[p] = s; tI[p] = idx;
}

__global__ void __launch_bounds__(256, 2) gemm_topk_kernel(
    const _Float16* __restrict__ Qh, const _Float16* __restrict__ Ql,
    const _Float16* __restrict__ Kh, const _Float16* __restrict__ Kl,
    float* __restrict__ pscore, int* __restrict__ pidx) {
  __shared__ _Float16 stAh[BM*32], stAl[BM*32], stBh[BN*32], stBl[BN*32];
  __shared__ float topS[128*33];
  __shared__ int   topI[128*33];
  __shared__ float candS[128*9];
  __shared__ int   candI[128*9];
  __shared__ float mS[128];
  __shared__ int   cnt[128];
  __shared__ int   sOver;

  const int tid  = threadIdx.x;
  const int lane = tid & 63;
  const int w    = tid >> 6;
  const int wr   = w >> 1, wc = w & 1;        // 64x64 wave tile
  const int cl   = lane & 15;                 // frag col/row lane
  const int g    = lane >> 4;                 // k-octet group
  const int g4   = g * 4;                     // C-frag row sub-base
  const int qbase  = blockIdx.x * BM;
  const int nbase0 = blockIdx.y * NRANGE;

  if (tid < 128) {
    mS[tid] = -INFINITY; cnt[tid] = 0;
#pragma unroll
    for (int j = 0; j < KTOP; ++j) { topS[tid*33+j] = -INFINITY; topI[tid*33+j] = 0x7fffffff; }
  }
  if (tid == 0) sOver = 0;
  __syncthreads();

  for (int ct = 0; ct < NTILES; ++ct) {
    const int n0 = nbase0 + ct * BN;
    f32x4 acc[4][4];
#pragma unroll
    for (int mi = 0; mi < 4; ++mi)
#pragma unroll
      for (int ni = 0; ni < 4; ++ni) acc[mi][ni] = (f32x4)0.0f;

    for (int ks = 0; ks < KSTEPS; ++ks) {
      const int kof = ks * 32;
      f16x8 ld[8];
#pragma unroll
      for (int p = 0; p < 2; ++p) {
        const int id = tid + p * 256;
        const int r = id >> 2, o = id & 3;
        const size_t ga = (size_t)(qbase + r) * DKK + kof + o * 8;
        const size_t gb = (size_t)(n0 + r) * DKK + kof + o * 8;
        ld[p*4+0] = *(const f16x8*)&Qh[ga];
        ld[p*4+1] = *(const f16x8*)&Ql[ga];
        ld[p*4+2] = *(const f16x8*)&Kh[gb];
        ld[p*4+3] = *(const f16x8*)&Kl[gb];
      }
      __syncthreads();           // previous step's LDS reads done
#pragma unroll
      for (int p = 0; p < 2; ++p) {
        const int id = tid + p * 256;
        const int r = id >> 2, o = id & 3;
        const int sw = r * 32 + 8 * (o ^ ((r >> 1) & 3));   // XOR swizzle, 2-way max
        *(f16x8*)&stAh[sw] = ld[p*4+0];
        *(f16x8*)&stAl[sw] = ld[p*4+1];
        *(f16x8*)&stBh[sw] = ld[p*4+2];
        *(f16x8*)&stBl[sw] = ld[p*4+3];
      }
      __syncthreads();

      f16x8 Ah[4], Al[4], Bh[4], Bl[4];
#pragma unroll
      for (int mi = 0; mi < 4; ++mi) {
        const int r = wr * 64 + mi * 16 + cl;
        const int sw = r * 32 + 8 * (g ^ ((r >> 1) & 3));
        Ah[mi] = *(const f16x8*)&stAh[sw];
        Al[mi] = *(const f16x8*)&stAl[sw];
      }
#pragma unroll
      for (int ni = 0; ni < 4; ++ni) {
        const int c = wc * 64 + ni * 16 + cl;
        const int sw = c * 32 + 8 * (g ^ ((c >> 1) & 3));
        Bh[ni] = *(const f16x8*)&stBh[sw];
        Bl[ni] = *(const f16x8*)&stBl[sw];
      }
#pragma unroll
      for (int mi = 0; mi < 4; ++mi)
#pragma unroll
        for (int ni = 0; ni < 4; ++ni) {
          acc[mi][ni] = __builtin_amdgcn_mfma_f32_16x16x32_f16(Al[mi], Bl[ni], acc[mi][ni], 0, 0, 0);
          acc[mi][ni] = __builtin_amdgcn_mfma_f32_16x16x32_f16(Al[mi], Bh[ni], acc[mi][ni], 0, 0, 0);
          acc[mi][ni] = __builtin_amdgcn_mfma_f32_16x16x32_f16(Ah[mi], Bl[ni], acc[mi][ni], 0, 0, 0);
          acc[mi][ni] = __builtin_amdgcn_mfma_f32_16x16x32_f16(Ah[mi], Bh[ni], acc[mi][ni], 0, 0, 0);
        }
    }

    // -------- candidate scan straight from accumulators --------
    // C layout (16x16): col = lane&15, row = (lane>>4)*4 + j  [guide §3]
    float m[4][4];
#pragma unroll
    for (int mi = 0; mi < 4; ++mi) {
      const f32x4 mv = *(const f32x4*)&mS[wr * 64 + mi * 16 + g4];
      m[mi][0] = mv[0]; m[mi][1] = mv[1]; m[mi][2] = mv[2]; m[mi][3] = mv[3];
    }
    unsigned long long pend = 0ull;
#pragma unroll
    for (int mi = 0; mi < 4; ++mi)
#pragma unroll
      for (int ni = 0; ni < 4; ++ni)
#pragma unroll
        for (int j = 0; j < 4; ++j)
          if (acc[mi][ni][j] >= m[mi][j])
            pend |= 1ull << (mi * 16 + ni * 4 + j);

    for (;;) {
      if (pend) {
#pragma unroll
        for (int mi = 0; mi < 4; ++mi)
#pragma unroll
          for (int ni = 0; ni < 4; ++ni)
#pragma unroll
            for (int j = 0; j < 4; ++j) {
              const int bit = mi * 16 + ni * 4 + j;
              if (pend & (1ull << bit)) {
                const int r = wr * 64 + mi * 16 + g4 + j;
                const int t = atomicAdd(&cnt[r], 1);
                if (t < CAP) {
                  candS[r * 9 + t] = acc[mi][ni][j];
                  candI[r * 9 + t] = n0 + wc * 64 + ni * 16 + cl;
                  pend &= ~(1ull << bit);
                }
              }
            }
      }
      __syncthreads();
      if (tid < 128) {
        int nc = cnt[tid];
        if (nc > CAP) { sOver = 1; nc = CAP; }
        float* tS = &topS[tid * 33];
        int*   tI = &topI[tid * 33];
        for (int e = 0; e < nc; ++e) insert32(tS, tI, candS[tid * 9 + e], candI[tid * 9 + e]);
        mS[tid] = tS[KTOP - 1];
        cnt[tid] = 0;
      }
      __syncthreads();
      const int over = sOver;
      __syncthreads();
      if (tid == 0) sOver = 0;
      if (!over) break;
      // threshold rose: prune pending
#pragma unroll
      for (int mi = 0; mi < 4; ++mi) {
        const f32x4 mv = *(const f32x4*)&mS[wr * 64 + mi * 16 + g4];
        m[mi][0] = mv[0]; m[mi][1] = mv[1]; m[mi][2] = mv[2]; m[mi][3] = mv[3];
      }
      unsigned long long keep = 0ull;
#pragma unroll
      for (int mi = 0; mi < 4; ++mi)
#pragma unroll
        for (int ni = 0; ni < 4; ++ni)
#pragma unroll
          for (int j = 0; j < 4; ++j) {
            const int bit = mi * 16 + ni * 4 + j;
            if ((pend & (1ull << bit)) && acc[mi][ni][j] >= m[mi][j])
              keep |= 1ull << bit;
          }
      pend = keep;
    }
  }

  if (tid < 128) {
    const size_t base = ((size_t)(qbase + tid) * NSPLIT + blockIdx.y) * KTOP;
    for (int j = 0; j < KTOP; ++j) {
      pscore[base + j] = topS[tid * 33 + j];
      pidx[base + j]   = topI[tid * 33 + j];
    }
  }
}

// ===================== FALLBACK (round-1, proven) =====================

#define QB 128
#define NB 128
#define KC 32
#define FNTILES (NRANGE / NB)
#define KCH (DKK / KC)
#define LDST 132

__global__ void __launch_bounds__(256) norm_kernel(
    const float* __restrict__ q, const float* __restrict__ keys,
    float* __restrict__ qn, float* __restrict__ kinv) {
  const int gw = (blockIdx.x * 256 + threadIdx.x) >> 6;
  const int lane = threadIdx.x & 63;
  if (gw < M_ROWS) {
    const float* row = q + (size_t)gw * DKK;
    float4 a = ((const float4*)row)[lane];
    float4 b = ((const float4*)row)[lane + 64];
    float s = a.x*a.x + a.y*a.y + a.z*a.z + a.w*a.w
            + b.x*b.x + b.y*b.y + b.z*b.z + b.w*b.w;
#pragma unroll
    for (int off = 32; off; off >>= 1) s += __shfl_xor(s, off);
    const float inv = 1.0f / fmaxf(sqrtf(s), 1e-12f);
    float* orow = qn + (size_t)gw * DKK;
    ((float4*)orow)[lane]      = make_float4(a.x*inv, a.y*inv, a.z*inv, a.w*inv);
    ((float4*)orow)[lane + 64] = make_float4(b.x*inv, b.y*inv, b.z*inv, b.w*inv);
  } else {
    const int n = gw - M_ROWS;
    if (n < N_KEYS) {
      const float* row = keys + (size_t)n * DKK;
      float4 a = ((const float4*)row)[lane];
      float4 b = ((const float4*)row)[lane + 64];
      float s = a.x*a.x + a.y*a.y + a.z*a.z + a.w*a.w
              + b.x*b.x + b.y*b.y + b.z*b.z + b.w*b.w;
#pragma unroll
      for (int off = 32; off; off >>= 1) s += __shfl_xor(s, off);
      if (lane == 0) kinv[n] = 1.0f / fmaxf(sqrtf(s), 1e-12f);
    }
  }
}

__device__ __forceinline__ void lds_wr_tile(float* dst, int k8, int r, float4 v, float scale) {
  dst[(k8 * 4 + 0) * LDST + r] = v.x * scale;
  dst[(k8 * 4 + 1) * LDST + r] = v.y * scale;
  dst[(k8 * 4 + 2) * LDST + r] = v.z * scale;
  dst[(k8 * 4 + 3) * LDST + r] = v.w * scale;
}

__global__ void __launch_bounds__(256, 1) score_topk_kernel(
    const float* __restrict__ qn, const float* __restrict__ keys,
    const float* __restrict__ kinv,
    float* __restrict__ pscore, int* __restrict__ pidx) {
  __shared__ float u[16896];
  __shared__ float topS[QB * KTOP];
  __shared__ int   topI[QB * KTOP];

  const int tid = threadIdx.x;
  const int tx = tid & 15, ty = tid >> 4;
  const int qbase = blockIdx.y * QB;
  const int nbase0 = blockIdx.x * NRANGE;

  for (int i = tid; i < QB * KTOP; i += 256) { topS[i] = -INFINITY; topI[i] = 0; }
  __syncthreads();

  for (int t = 0; t < FNTILES; ++t) {
    const int n0 = nbase0 + t * NB;
    float acc[8][8];
#pragma unroll
    for (int i = 0; i < 8; ++i)
#pragma unroll
      for (int j = 0; j < 8; ++j) acc[i][j] = 0.0f;

#pragma unroll
    for (int p = 0; p < 4; ++p) {
      const int id = tid + p * 256;
      const int r = id >> 3, k8 = id & 7;
      const float4 va = *(const float4*)&qn[(size_t)(qbase + r) * DKK + k8 * 4];
      const float4 vb = *(const float4*)&keys[(size_t)(n0 + r) * DKK + k8 * 4];
      const float kv = kinv[n0 + r];
      lds_wr_tile(u, k8, r, va, 1.0f);
      lds_wr_tile(u + 4224, k8, r, vb, kv);
    }
    __syncthreads();

    for (int kc = 0; kc < KCH; ++kc) {
      float4 pa[4], pb[4]; float pk[4];
      const bool pre = (kc + 1 < KCH);
      if (pre) {
#pragma unroll
        for (int p = 0; p < 4; ++p) {
          const int id = tid + p * 256;
          const int r = id >> 3, k8 = id & 7;
          pa[p] = *(const float4*)&qn[(size_t)(qbase + r) * DKK + (kc + 1) * KC + k8 * 4];
          pb[p] = *(const float4*)&keys[(size_t)(n0 + r) * DKK + (kc + 1) * KC + k8 * 4];
          pk[p] = kinv[n0 + r];
        }
      }
      const float* As = u + (kc & 1) * 8448;
      const float* Bs = As + 4224;
#pragma unroll 4
      for (int kk = 0; kk < KC; ++kk) {
        const float4 a0 = *(const float4*)&As[kk * LDST + ty * 4];
        const float4 a1 = *(const float4*)&As[kk * LDST + ty * 4 + 64];
        const float4 b0 = *(const float4*)&Bs[kk * LDST + tx * 4];
        const float4 b1 = *(const float4*)&Bs[kk * LDST + tx * 4 + 64];
        const float av[8] = {a0.x,a0.y,a0.z,a0.w,a1.x,a1.y,a1.z,a1.w};
        const float bv[8] = {b0.x,b0.y,b0.z,b0.w,b1.x,b1.y,b1.z,b1.w};
#pragma unroll
        for (int i = 0; i < 8; ++i)
#pragma unroll
          for (int j = 0; j < 8; ++j)
            acc[i][j] = fmaf(av[i], bv[j], acc[i][j]);
      }
      if (pre) {
        float* Ad = u + ((kc + 1) & 1) * 8448;
        float* Bd = Ad + 4224;
#pragma unroll
        for (int p = 0; p < 4; ++p) {
          const int id = tid + p * 256;
          const int r = id >> 3, k8 = id & 7;
          lds_wr_tile(Ad, k8, r, pa[p], 1.0f);
          lds_wr_tile(Bd, k8, r, pb[p], pk[p]);
        }
      }
      __syncthreads();
    }

#pragma unroll
    for (int ib = 0; ib < 2; ++ib)
#pragma unroll
      for (int i = 0; i < 4; ++i) {
        const int r = ty * 4 + i + ib * 64;
#pragma unroll
        for (int jb = 0; jb < 2; ++jb) {
          *(float4*)&u[r * LDST + tx * 4 + jb * 64] =
              make_float4(acc[ib*4+i][jb*4+0], acc[ib*4+i][jb*4+1],
                          acc[ib*4+i][jb*4+2], acc[ib*4+i][jb*4+3]);
        }
      }
    __syncthreads();

    if (tid < QB) {
      const int row = tid;
      float* tS = &topS[row * KTOP];
      int*   tI = &topI[row * KTOP];
      float mSv = tS[KTOP - 1]; int mIv = tI[KTOP - 1];
      for (int c4 = 0; c4 < NB / 4; ++c4) {
        const float4 v = *(const float4*)&u[row * LDST + c4 * 4];
#pragma unroll
        for (int wv = 0; wv < 4; ++wv) {
          const float s = (&v.x)[wv];
          const int idx = n0 + c4 * 4 + wv;
          if (s > mSv || (s == mSv && idx < mIv)) {
            int p = 0;
            while (p < KTOP && (tS[p] > s || (tS[p] == s && tI[p] < idx))) ++p;
            for (int qq = KTOP - 1; qq > p; --qq) { tS[qq] = tS[qq-1]; tI[qq] = tI[qq-1]; }
            tS[p] = s; tI[p] = idx;
            mSv = tS[KTOP - 1]; mIv = tI[KTOP - 1];
          }
        }
      }
    }
    __syncthreads();
  }

  if (tid < QB) {
    const size_t base = ((size_t)(qbase + tid) * NSPLIT + blockIdx.x) * KTOP;
    for (int j = 0; j < KTOP; ++j) {
      pscore[base + j] = topS[tid * KTOP + j];
      pidx[base + j]   = topI[tid * KTOP + j];
    }
  }
}

// ---------- shared: merge 32 sorted partial lists, softmax, gather ----------
__global__ void __launch_bounds__(256) merge_kernel(
    const float* __restrict__ pscore, const int* __restrict__ pidx,
    const float* __restrict__ values,
    float* __restrict__ out_agg, float* __restrict__ out_attn, float* __restrict__ out_idx) {
  __shared__ float attn_s[KTOP];
  __shared__ int   sel_i[KTOP];
  const int row = blockIdx.x;
  const int tid = threadIdx.x;

  if (tid < 64) {
    const int lane = tid;
    const float* ps = pscore + (size_t)row * NSPLIT * KTOP;
    const int*   pi = pidx   + (size_t)row * NSPLIT * KTOP;
    int pos = 0;
    float s; int idx;
    if (lane < NSPLIT) { s = ps[lane * KTOP]; idx = pi[lane * KTOP]; }
    else { s = -INFINITY; idx = 0x7fffffff; }
    for (int it = 0; it < KTOP; ++it) {
      float wsv = s; int wi = idx; int wl = lane;
#pragma unroll
      for (int off = 32; off; off >>= 1) {
        const float os = __shfl_xor(wsv, off);
        const int   oi = __shfl_xor(wi, off);
        const int   ol = __shfl_xor(wl, off);
        if (os > wsv || (os == wsv && oi < wi)) { wsv = os; wi = oi; wl = ol; }
      }
      if (lane == 0) { attn_s[it] = wsv; sel_i[it] = wi; }
      if (lane == wl) {
        ++pos;
        if (pos < KTOP) { s = ps[lane * KTOP + pos]; idx = pi[lane * KTOP + pos]; }
        else { s = -INFINITY; idx = 0x7fffffff; }
      }
    }
  }
  __syncthreads();
  if (tid < KTOP) {
    const float mm = attn_s[0];
    const float e = expf((attn_s[tid] - mm) * 10.0f);
    float tsum = e;
#pragma unroll
    for (int off = 16; off; off >>= 1) tsum += __shfl_xor(tsum, off);
    const float a = e / tsum;
    out_attn[(size_t)row * KTOP + tid] = a;
    out_idx [(size_t)row * KTOP + tid] = (float)sel_i[tid];
    attn_s[tid] = a;
  }
  __syncthreads();

  const int d = tid * 2;
  float2 accv = make_float2(0.0f, 0.0f);
  for (int j = 0; j < KTOP; ++j) {
    const float wgt = attn_s[j];
    const float2 v = *(const float2*)&values[(size_t)sel_i[j] * DVV + d];
    accv.x = fmaf(wgt, v.x, accv.x);
    accv.y = fmaf(wgt, v.y, accv.y);
  }
  *(float2*)&out_agg[(size_t)row * DVV + d] = accv;
}

extern "C" void kernel_launch(void* const* d_in, const int* in_sizes, int n_in,
                              void* d_out, int out_size, void* d_ws, size_t ws_size,
                              hipStream_t stream) {
  const float* q      = (const float*)d_in[0];
  const float* keys   = (const float*)d_in[1];
  const float* values = (const float*)d_in[2];

  float* out      = (float*)d_out;
  float* out_agg  = out;
  float* out_attn = out + (size_t)M_ROWS * DVV;
  float* out_idx  = out_attn + (size_t)M_ROWS * KTOP;

  const size_t needFast =
      (size_t)M_ROWS * DKK * 2 * 2      // Qh,Ql
    + (size_t)N_KEYS * DKK * 2 * 2      // Kh,Kl
    + (size_t)M_ROWS * NSPLIT * KTOP * 8;  // pscore+pidx

  if (ws_size >= needFast) {
    _Float16* Qh = (_Float16*)d_ws;
    _Float16* Ql = Qh + (size_t)M_ROWS * DKK;
    _Float16* Kh = Ql + (size_t)M_ROWS * DKK;
    _Float16* Kl = Kh + (size_t)N_KEYS * DKK;
    float* pscore = (float*)(Kl + (size_t)N_KEYS * DKK);
    int*   pidx   = (int*)(pscore + (size_t)M_ROWS * NSPLIT * KTOP);

    norm_split_kernel<<<(M_ROWS + N_KEYS) / 4, 256, 0, stream>>>(q, keys, Qh, Ql, Kh, Kl);
    dim3 g2(M_ROWS / BM, NSPLIT, 1);
    gemm_topk_kernel<<<g2, 256, 0, stream>>>(Qh, Ql, Kh, Kl, pscore, pidx);
    merge_kernel<<<M_ROWS, 256, 0, stream>>>(pscore, pidx, values, out_agg, out_attn, out_idx);
  } else {
    float* ws     = (float*)d_ws;
    float* qn     = ws;
    float* kinv   = qn + (size_t)M_ROWS * DKK;
    float* pscore = kinv + N_KEYS;
    int*   pidx   = (int*)(pscore + (size_t)M_ROWS * NSPLIT * KTOP);

    norm_kernel<<<(M_ROWS + N_KEYS) / 4, 256, 0, stream>>>(q, keys, qn, kinv);
    dim3 g2(NSPLIT, M_ROWS / QB, 1);
    score_topk_kernel<<<g2, 256, 0, stream>>>(qn, keys, kinv, pscore, pidx);
    merge_kernel<<<M_ROWS, 256, 0, stream>>>(pscore, pidx, values, out_agg, out_attn, out_idx);
  }
}